// Round 1
// baseline (182.517 us; speedup 1.0000x reference)
//
#include <hip/hip_runtime.h>
#include <math.h>

#define BB 8
#define CDIM 256
#define CCH 64
#define HDIM 64
#define WDIM 64
#define KJ 36           // S*S*K*K
#define EPSV 1e-5f

// ---------------- K1: 1x1 conv (C=256 -> CC=64) ----------------
__global__ __launch_bounds__(256) void k1_conv1x1(const float* __restrict__ x,
                                                  const float* __restrict__ w1,
                                                  const float* __restrict__ b1,
                                                  float* __restrict__ comp) {
    __shared__ float xs[CDIM * WDIM];          // 64 KB: x[b, :, h, :]
    const int bh = blockIdx.x;                  // b*64 + h
    const int b = bh >> 6, h = bh & 63;
    const int t = threadIdx.x;

    const float* xrow = x + ((size_t)b * CDIM) * HDIM * WDIM + (size_t)h * WDIM;
    for (int e = t; e < CDIM * WDIM; e += 256) {
        int c = e >> 6, w = e & 63;
        xs[e] = xrow[(size_t)c * HDIM * WDIM + w];
    }
    __syncthreads();

    const int w = t & 63;
    const int og = __builtin_amdgcn_readfirstlane(t >> 6);   // wave-uniform o-group
    float acc[16];
#pragma unroll
    for (int oi = 0; oi < 16; ++oi) acc[oi] = 0.f;

    const float* w1p = w1 + (size_t)og * 16 * CDIM;
#pragma unroll 4
    for (int c = 0; c < CDIM; ++c) {
        float xv = xs[c * WDIM + w];
#pragma unroll
        for (int oi = 0; oi < 16; ++oi)
            acc[oi] += xv * w1p[oi * CDIM + c];
    }
#pragma unroll
    for (int oi = 0; oi < 16; ++oi) {
        int o = og * 16 + oi;
        comp[(((size_t)b * CCH + o) * HDIM + h) * WDIM + w] = acc[oi] + b1[o];
    }
}

// ---------------- K2: per-channel batch stats (mean, rsqrt(var+eps)) ----------------
__global__ __launch_bounds__(256) void k2_stats(const float* __restrict__ comp,
                                                float* __restrict__ stats) {
    const int o = blockIdx.x;
    const int t = threadIdx.x;
    float s = 0.f, q = 0.f;
    for (int b = 0; b < BB; ++b) {
        const float* p = comp + ((size_t)b * CCH + o) * HDIM * WDIM;
        for (int e = t; e < HDIM * WDIM; e += 256) {
            float v = p[e];
            s += v; q += v * v;
        }
    }
#pragma unroll
    for (int off = 32; off >= 1; off >>= 1) {
        s += __shfl_down(s, off, 64);
        q += __shfl_down(q, off, 64);
    }
    __shared__ float ls[8];
    const int wave = t >> 6, lane = t & 63;
    if (lane == 0) { ls[wave] = s; ls[4 + wave] = q; }
    __syncthreads();
    if (t == 0) {
        float S = ls[0] + ls[1] + ls[2] + ls[3];
        float Q = ls[4] + ls[5] + ls[6] + ls[7];
        const float N = (float)(BB * HDIM * WDIM);
        float mu = S / N;
        float var = Q / N - mu * mu;
        stats[o] = mu;
        stats[CCH + o] = rsqrtf(var + EPSV);
    }
}

// ---------------- K3: BN+ReLU (on read) + 3x3 conv (zero pad) ----------------
__global__ __launch_bounds__(256) void k3_conv3(const float* __restrict__ comp,
                                                const float* __restrict__ stats,
                                                const float* __restrict__ gamma,
                                                const float* __restrict__ beta,
                                                const float* __restrict__ w2,
                                                const float* __restrict__ b2,
                                                float* __restrict__ enc) {
    __shared__ float cs[3][CCH][WDIM];         // 48 KB: rows h-1, h, h+1 post-BN/ReLU
    const int bh = blockIdx.x;
    const int b = bh >> 6, h = bh & 63;
    const int t = threadIdx.x;

    for (int e = t; e < 3 * CCH * WDIM; e += 256) {
        int dy = e / (CCH * WDIM);
        int rem = e % (CCH * WDIM);
        int o = rem >> 6, w = rem & 63;
        int hh = h + dy - 1;
        float v = 0.f;
        if (hh >= 0 && hh < HDIM) {
            float raw = comp[(((size_t)b * CCH + o) * HDIM + hh) * WDIM + w];
            v = (raw - stats[o]) * stats[CCH + o] * gamma[o] + beta[o];
            v = fmaxf(v, 0.f);
        }
        cs[dy][o][w] = v;
    }
    __syncthreads();

    const int w = t & 63;
    const int jg = __builtin_amdgcn_readfirstlane(t >> 6);   // 0..3, 9 j's each
    float acc[9];
#pragma unroll
    for (int ji = 0; ji < 9; ++ji) acc[ji] = b2[jg * 9 + ji];

    for (int o = 0; o < CCH; ++o) {
#pragma unroll
        for (int dy = 0; dy < 3; ++dy) {
            float vm1 = (w > 0)  ? cs[dy][o][w - 1] : 0.f;
            float v0  = cs[dy][o][w];
            float vp1 = (w < 63) ? cs[dy][o][w + 1] : 0.f;
#pragma unroll
            for (int ji = 0; ji < 9; ++ji) {
                int j = jg * 9 + ji;
                const float* wp = w2 + (((size_t)j * CCH + o) * 3 + dy) * 3;
                acc[ji] += vm1 * wp[0] + v0 * wp[1] + vp1 * wp[2];
            }
        }
    }
#pragma unroll
    for (int ji = 0; ji < 9; ++ji) {
        int j = jg * 9 + ji;
        enc[(((size_t)b * KJ + j) * HDIM + h) * WDIM + w] = acc[ji];
    }
}

// ---------------- K4: softmax over H axis; emit (b,h,w,36) layout ----------------
__global__ __launch_bounds__(64) void k4_softmax(const float* __restrict__ enc,
                                                 float* __restrict__ kern_s) {
    const int bj = blockIdx.x;                  // b*36 + j
    const int b = bj / KJ, j = bj % KJ;
    const int w = threadIdx.x;
    const float* p = enc + ((size_t)b * KJ + j) * HDIM * WDIM + w;
    float v[64];
    float m = -1e30f;
#pragma unroll
    for (int h = 0; h < 64; ++h) { v[h] = p[h * WDIM]; m = fmaxf(m, v[h]); }
    float sum = 0.f;
#pragma unroll
    for (int h = 0; h < 64; ++h) { v[h] = __expf(v[h] - m); sum += v[h]; }
    float inv = 1.f / sum;
#pragma unroll
    for (int h = 0; h < 64; ++h) {
        kern_s[(((size_t)b * HDIM + h) * WDIM + w) * KJ + j] = v[h] * inv;
    }
}

// ---------------- K5: CARAFE gather + pixel-shuffle-style scatter ----------------
__global__ __launch_bounds__(256) void k5_carafe(const float* __restrict__ x,
                                                 const float* __restrict__ kern_s,
                                                 float* __restrict__ out) {
    __shared__ float ks[KJ][WDIM];              // 9 KB, transposed for bank-free reads
    const int bh = blockIdx.x;                  // b*64 + h
    const int b = bh >> 6, h = bh & 63;
    const int t = threadIdx.x;

    const float* kp = kern_s + (size_t)bh * (WDIM * KJ);
    for (int e = t; e < WDIM * KJ; e += 256) {
        int pix = e / KJ, j = e % KJ;
        ks[j][pix] = kp[e];
    }
    __syncthreads();

    const int w = t & 63;
    const int cg = t >> 6;                      // channel chunk 0..3 (64 each)

    float kern[KJ];
#pragma unroll
    for (int j = 0; j < KJ; ++j) kern[j] = ks[j][w];

    const int hm1 = (h > 0) ? h - 1 : 0, hp1 = (h < 63) ? h + 1 : 63;
    const int wm1 = (w > 0) ? w - 1 : 0, wp1 = (w < 63) ? w + 1 : 63;
    const int rows[3] = {hm1, h, hp1};
    const int cols[3] = {wm1, w, wp1};

    for (int ci = 0; ci < 64; ++ci) {
        int c = cg * 64 + ci;
        const float* xb = x + ((size_t)b * CDIM + c) * HDIM * WDIM;
        float tap[9];
#pragma unroll
        for (int dy = 0; dy < 3; ++dy)
#pragma unroll
            for (int dx = 0; dx < 3; ++dx)
                tap[dy * 3 + dx] = xb[rows[dy] * WDIM + cols[dx]];

        float o0 = 0.f, o1 = 0.f, o2 = 0.f, o3 = 0.f;
#pragma unroll
        for (int k = 0; k < 9; ++k) {
            float tv = tap[k];
            o0 += tv * kern[0 * 9 + k];
            o1 += tv * kern[1 * 9 + k];
            o2 += tv * kern[2 * 9 + k];
            o3 += tv * kern[3 * 9 + k];
        }
        // out[b, s*64 + c/4, 2h + ((c>>1)&1), (c&1)*64 + w]
        int c2b = c >> 2;
        int hs = 2 * h + ((c >> 1) & 1);
        int wsx = (c & 1) * 64 + w;
        size_t base = ((size_t)b * CDIM) * (128 * 128) + (size_t)hs * 128 + wsx;
        out[base + (size_t)(0 * 64 + c2b) * (128 * 128)] = o0;
        out[base + (size_t)(1 * 64 + c2b) * (128 * 128)] = o1;
        out[base + (size_t)(2 * 64 + c2b) * (128 * 128)] = o2;
        out[base + (size_t)(3 * 64 + c2b) * (128 * 128)] = o3;
    }
}

extern "C" void kernel_launch(void* const* d_in, const int* in_sizes, int n_in,
                              void* d_out, int out_size, void* d_ws, size_t ws_size,
                              hipStream_t stream) {
    const float* x     = (const float*)d_in[0];
    const float* w1    = (const float*)d_in[1];
    const float* b1    = (const float*)d_in[2];
    const float* gamma = (const float*)d_in[3];
    const float* beta  = (const float*)d_in[4];
    const float* w2    = (const float*)d_in[5];
    const float* b2    = (const float*)d_in[6];
    float* out = (float*)d_out;

    char* ws = (char*)d_ws;
    float* comp  = (float*)(ws);                       // 8*64*64*64*4   = 8,388,608 B
    float* enc   = (float*)(ws + 8388608);             // 8*36*64*64*4   = 4,718,592 B
    float* kern  = (float*)(ws + 13107200);            // 8*64*64*36*4   = 4,718,592 B
    float* stats = (float*)(ws + 17825792);            // 128 floats

    hipLaunchKernelGGL(k1_conv1x1, dim3(BB * HDIM), dim3(256), 0, stream, x, w1, b1, comp);
    hipLaunchKernelGGL(k2_stats,   dim3(CCH),       dim3(256), 0, stream, comp, stats);
    hipLaunchKernelGGL(k3_conv3,   dim3(BB * HDIM), dim3(256), 0, stream, comp, stats, gamma, beta, w2, b2, enc);
    hipLaunchKernelGGL(k4_softmax, dim3(BB * KJ),   dim3(64),  0, stream, enc, kern);
    hipLaunchKernelGGL(k5_carafe,  dim3(BB * HDIM), dim3(256), 0, stream, x, kern, out);
}

// Round 2
// 133.149 us; speedup vs baseline: 1.3708x; 1.3708x over previous
//
#include <hip/hip_runtime.h>
#include <math.h>

#define BB 8
#define CDIM 256
#define CCH 64
#define HDIM 64
#define WDIM 64
#define KJ 36           // S*S*K*K
#define EPSV 1e-5f

// ---------------- K1: 1x1 conv (C=256 -> CC=64) ----------------
__global__ __launch_bounds__(256) void k1_conv1x1(const float* __restrict__ x,
                                                  const float* __restrict__ w1,
                                                  const float* __restrict__ b1,
                                                  float* __restrict__ comp) {
    __shared__ float xs[CDIM * WDIM];          // 64 KB: x[b, :, h, :]
    const int bh = blockIdx.x;                  // b*64 + h
    const int b = bh >> 6, h = bh & 63;
    const int t = threadIdx.x;

    const float* xrow = x + ((size_t)b * CDIM) * HDIM * WDIM + (size_t)h * WDIM;
    // float4 staging: 256 channels x 16 float4 each
    for (int e = t; e < CDIM * 16; e += 256) {
        int c = e >> 4, q = e & 15;
        float4 f = *(const float4*)(xrow + (size_t)c * HDIM * WDIM + q * 4);
        *(float4*)(xs + c * WDIM + q * 4) = f;
    }
    __syncthreads();

    const int w = t & 63;
    const int og = __builtin_amdgcn_readfirstlane(t >> 6);   // wave-uniform o-group
    float acc[16];
#pragma unroll
    for (int oi = 0; oi < 16; ++oi) acc[oi] = 0.f;

    const float* w1p = w1 + (size_t)og * 16 * CDIM;
#pragma unroll 4
    for (int c = 0; c < CDIM; ++c) {
        float xv = xs[c * WDIM + w];
#pragma unroll
        for (int oi = 0; oi < 16; ++oi)
            acc[oi] += xv * w1p[oi * CDIM + c];
    }
#pragma unroll
    for (int oi = 0; oi < 16; ++oi) {
        int o = og * 16 + oi;
        comp[(((size_t)b * CCH + o) * HDIM + h) * WDIM + w] = acc[oi] + b1[o];
    }
}

// ---------------- K2: per-(b,o) partial sums (deterministic, no atomics) ----------------
__global__ __launch_bounds__(256) void k2_partial(const float* __restrict__ comp,
                                                  float* __restrict__ psum,
                                                  float* __restrict__ psq) {
    const int bid = blockIdx.x;                 // b*64 + o
    const int t = threadIdx.x;
    const float4* p = (const float4*)(comp + (size_t)bid * HDIM * WDIM);
    float s = 0.f, q = 0.f;
#pragma unroll
    for (int i = 0; i < 4; ++i) {
        float4 v = p[t + i * 256];
        s += v.x + v.y + v.z + v.w;
        q += v.x * v.x + v.y * v.y + v.z * v.z + v.w * v.w;
    }
#pragma unroll
    for (int off = 32; off >= 1; off >>= 1) {
        s += __shfl_down(s, off, 64);
        q += __shfl_down(q, off, 64);
    }
    __shared__ float ls[8];
    const int wave = t >> 6, lane = t & 63;
    if (lane == 0) { ls[wave] = s; ls[4 + wave] = q; }
    __syncthreads();
    if (t == 0) {
        psum[bid] = ls[0] + ls[1] + ls[2] + ls[3];
        psq[bid]  = ls[4] + ls[5] + ls[6] + ls[7];
    }
}

// ---------------- K3: finalize BN + BN/ReLU on read + 3x3 conv (zero pad) ----------------
__global__ __launch_bounds__(256) void k3_conv3(const float* __restrict__ comp,
                                                const float* __restrict__ psum,
                                                const float* __restrict__ psq,
                                                const float* __restrict__ gamma,
                                                const float* __restrict__ beta,
                                                const float* __restrict__ w2,
                                                const float* __restrict__ b2,
                                                float* __restrict__ enc) {
    __shared__ float cs[3][CCH][WDIM];         // 48 KB: rows h-1, h, h+1 post-BN/ReLU
    __shared__ float a_s[CCH], c_s[CCH];       // BN scale/shift
    const int bh = blockIdx.x;
    const int b = bh >> 6, h = bh & 63;
    const int t = threadIdx.x;

    if (t < CCH) {
        float S = 0.f, Q = 0.f;
#pragma unroll
        for (int b2 = 0; b2 < BB; ++b2) { S += psum[b2 * CCH + t]; Q += psq[b2 * CCH + t]; }
        const float N = (float)(BB * HDIM * WDIM);
        float mu = S / N;
        float var = Q / N - mu * mu;
        float rs = rsqrtf(var + EPSV);
        float a = rs * gamma[t];
        a_s[t] = a;
        c_s[t] = beta[t] - mu * a;
    }
    __syncthreads();

    // float4 staging: 3 rows x 64 ch x 16 float4
    for (int e = t; e < 3 * CCH * 16; e += 256) {
        int dy = e >> 10;                       // e / 1024
        int rem = e & 1023;
        int o = rem >> 4, q = rem & 15;
        int hh = h + dy - 1;
        float4 v = make_float4(0.f, 0.f, 0.f, 0.f);
        if (hh >= 0 && hh < HDIM) {
            float4 raw = *(const float4*)(comp + (((size_t)b * CCH + o) * HDIM + hh) * WDIM + q * 4);
            float a = a_s[o], c = c_s[o];
            v.x = fmaxf(raw.x * a + c, 0.f);
            v.y = fmaxf(raw.y * a + c, 0.f);
            v.z = fmaxf(raw.z * a + c, 0.f);
            v.w = fmaxf(raw.w * a + c, 0.f);
        }
        *(float4*)(&cs[dy][o][q * 4]) = v;
    }
    __syncthreads();

    const int w = t & 63;
    const int jg = __builtin_amdgcn_readfirstlane(t >> 6);   // 0..3, 9 j's each
    float acc[9];
#pragma unroll
    for (int ji = 0; ji < 9; ++ji) acc[ji] = b2[jg * 9 + ji];

    for (int o = 0; o < CCH; ++o) {
#pragma unroll
        for (int dy = 0; dy < 3; ++dy) {
            float vm1 = (w > 0)  ? cs[dy][o][w - 1] : 0.f;
            float v0  = cs[dy][o][w];
            float vp1 = (w < 63) ? cs[dy][o][w + 1] : 0.f;
#pragma unroll
            for (int ji = 0; ji < 9; ++ji) {
                int j = jg * 9 + ji;
                const float* wp = w2 + (((size_t)j * CCH + o) * 3 + dy) * 3;
                acc[ji] += vm1 * wp[0] + v0 * wp[1] + vp1 * wp[2];
            }
        }
    }
#pragma unroll
    for (int ji = 0; ji < 9; ++ji) {
        int j = jg * 9 + ji;
        enc[(((size_t)b * KJ + j) * HDIM + h) * WDIM + w] = acc[ji];
    }
}

// ---------------- K4: softmax column stats over H per (b,j,w) ----------------
__global__ __launch_bounds__(256) void k4_smstats(const float* __restrict__ enc,
                                                  float* __restrict__ mx,
                                                  float* __restrict__ ivs) {
    const int bj = blockIdx.x;                  // b*36 + j
    const int t = threadIdx.x;
    const int w = t & 63, q = t >> 6;
    const float* p = enc + (size_t)bj * HDIM * WDIM + (size_t)q * 16 * WDIM + w;
    float v[16];
    float lm = -1e30f;
#pragma unroll
    for (int i = 0; i < 16; ++i) { v[i] = p[i * WDIM]; lm = fmaxf(lm, v[i]); }

    __shared__ float red[4][WDIM];
    red[q][w] = lm;
    __syncthreads();
    float gm = fmaxf(fmaxf(red[0][w], red[1][w]), fmaxf(red[2][w], red[3][w]));
    __syncthreads();
    float ls = 0.f;
#pragma unroll
    for (int i = 0; i < 16; ++i) ls += __expf(v[i] - gm);
    red[q][w] = ls;
    __syncthreads();
    if (q == 0) {
        float s = red[0][w] + red[1][w] + red[2][w] + red[3][w];
        mx[(size_t)bj * WDIM + w] = gm;
        ivs[(size_t)bj * WDIM + w] = 1.f / s;
    }
}

// ---------------- K5: CARAFE gather + pixel-shuffle-style scatter ----------------
__global__ __launch_bounds__(256) void k5_carafe(const float* __restrict__ x,
                                                 const float* __restrict__ enc,
                                                 const float* __restrict__ mx,
                                                 const float* __restrict__ ivs,
                                                 float* __restrict__ out) {
    __shared__ float ks[KJ][WDIM];              // 9 KB softmaxed kernels for this (b,h)
    const int bh = blockIdx.x;                  // b*64 + h
    const int b = bh >> 6, h = bh & 63;
    const int t = threadIdx.x;

    // stage + softmax-apply: 36*64 values, coalesced over w
    for (int e = t; e < KJ * WDIM; e += 256) {
        int j = e >> 6, w = e & 63;
        size_t bjw = ((size_t)b * KJ + j) * WDIM + w;
        float raw = enc[((size_t)b * KJ + j) * HDIM * WDIM + (size_t)h * WDIM + w];
        ks[j][w] = __expf(raw - mx[bjw]) * ivs[bjw];
    }
    __syncthreads();

    const int w = t & 63;
    const int cg = t >> 6;                      // channel chunk 0..3 (64 each)

    float kern[KJ];
#pragma unroll
    for (int j = 0; j < KJ; ++j) kern[j] = ks[j][w];

    const int hm1 = (h > 0) ? h - 1 : 0, hp1 = (h < 63) ? h + 1 : 63;
    const int wm1 = (w > 0) ? w - 1 : 0, wp1 = (w < 63) ? w + 1 : 63;

    for (int ci = 0; ci < 64; ++ci) {
        int c = cg * 64 + ci;
        const float* xb = x + ((size_t)b * CDIM + c) * HDIM * WDIM;
        // 3 row loads; left/right taps via wave shuffle (row == one wave)
        float r0 = xb[hm1 * WDIM + w];
        float r1 = xb[h   * WDIM + w];
        float r2 = xb[hp1 * WDIM + w];
        float tap[9];
        tap[0] = __shfl(r0, wm1, 64); tap[1] = r0; tap[2] = __shfl(r0, wp1, 64);
        tap[3] = __shfl(r1, wm1, 64); tap[4] = r1; tap[5] = __shfl(r1, wp1, 64);
        tap[6] = __shfl(r2, wm1, 64); tap[7] = r2; tap[8] = __shfl(r2, wp1, 64);

        float o0 = 0.f, o1 = 0.f, o2 = 0.f, o3 = 0.f;
#pragma unroll
        for (int k = 0; k < 9; ++k) {
            float tv = tap[k];
            o0 += tv * kern[0 * 9 + k];
            o1 += tv * kern[1 * 9 + k];
            o2 += tv * kern[2 * 9 + k];
            o3 += tv * kern[3 * 9 + k];
        }
        // out[b, s*64 + c/4, 2h + ((c>>1)&1), (c&1)*64 + w]
        int c2b = c >> 2;
        int hs = 2 * h + ((c >> 1) & 1);
        int wsx = (c & 1) * 64 + w;
        size_t base = ((size_t)b * CDIM) * (128 * 128) + (size_t)hs * 128 + wsx;
        out[base + (size_t)(0 * 64 + c2b) * (128 * 128)] = o0;
        out[base + (size_t)(1 * 64 + c2b) * (128 * 128)] = o1;
        out[base + (size_t)(2 * 64 + c2b) * (128 * 128)] = o2;
        out[base + (size_t)(3 * 64 + c2b) * (128 * 128)] = o3;
    }
}

extern "C" void kernel_launch(void* const* d_in, const int* in_sizes, int n_in,
                              void* d_out, int out_size, void* d_ws, size_t ws_size,
                              hipStream_t stream) {
    const float* x     = (const float*)d_in[0];
    const float* w1    = (const float*)d_in[1];
    const float* b1    = (const float*)d_in[2];
    const float* gamma = (const float*)d_in[3];
    const float* beta  = (const float*)d_in[4];
    const float* w2    = (const float*)d_in[5];
    const float* b2    = (const float*)d_in[6];
    float* out = (float*)d_out;

    char* ws = (char*)d_ws;
    float* comp  = (float*)(ws);                       // 8*64*64*64*4 = 8,388,608 B
    float* enc   = (float*)(ws + 8388608);             // 8*36*64*64*4 = 4,718,592 B
    float* mx    = (float*)(ws + 13107200);            // 8*36*64*4    = 73,728 B
    float* ivs   = (float*)(ws + 13180928);            // 73,728 B
    float* psum  = (float*)(ws + 13254656);            // 512*4 = 2,048 B
    float* psq   = (float*)(ws + 13256704);            // 2,048 B

    hipLaunchKernelGGL(k1_conv1x1, dim3(BB * HDIM), dim3(256), 0, stream, x, w1, b1, comp);
    hipLaunchKernelGGL(k2_partial, dim3(BB * CCH),  dim3(256), 0, stream, comp, psum, psq);
    hipLaunchKernelGGL(k3_conv3,   dim3(BB * HDIM), dim3(256), 0, stream, comp, psum, psq, gamma, beta, w2, b2, enc);
    hipLaunchKernelGGL(k4_smstats, dim3(BB * KJ),   dim3(256), 0, stream, enc, mx, ivs);
    hipLaunchKernelGGL(k5_carafe,  dim3(BB * HDIM), dim3(256), 0, stream, x, enc, mx, ivs, out);
}

// Round 3
// 118.351 us; speedup vs baseline: 1.5422x; 1.1250x over previous
//
#include <hip/hip_runtime.h>
#include <math.h>

#define BB 8
#define CDIM 256
#define CCH 64
#define HDIM 64
#define WDIM 64
#define KJ 36           // S*S*K*K
#define EPSV 1e-5f

// ---------------- K1: 1x1 conv (C=256 -> CC=64), two-phase LDS, fused row stats ----------------
__global__ __launch_bounds__(256) void k1_conv1x1(const float* __restrict__ x,
                                                  const float* __restrict__ w1,
                                                  const float* __restrict__ b1,
                                                  float* __restrict__ comp,
                                                  float* __restrict__ rowsum,
                                                  float* __restrict__ rowsq) {
    __shared__ float xs[128 * WDIM];            // 32 KB: half the channels of x[b,:,h,:]
    const int bh = blockIdx.x;                  // b*64 + h
    const int b = bh >> 6, h = bh & 63;
    const int t = threadIdx.x;
    const int w = t & 63;
    const int og = __builtin_amdgcn_readfirstlane(t >> 6);   // wave-uniform o-group

    float acc[16];
#pragma unroll
    for (int oi = 0; oi < 16; ++oi) acc[oi] = 0.f;

    const float* xrow = x + ((size_t)b * CDIM) * HDIM * WDIM + (size_t)h * WDIM;

    for (int ph = 0; ph < 2; ++ph) {
        if (ph) __syncthreads();
        for (int e = t; e < 128 * 16; e += 256) {
            int c = e >> 4, q = e & 15;
            *(float4*)(xs + c * WDIM + q * 4) =
                *(const float4*)(xrow + (size_t)(ph * 128 + c) * HDIM * WDIM + q * 4);
        }
        __syncthreads();

        const float* w1p = w1 + (size_t)og * 16 * CDIM + ph * 128;
#pragma unroll 4
        for (int c = 0; c < 128; ++c) {
            float xv = xs[c * WDIM + w];
#pragma unroll
            for (int oi = 0; oi < 16; ++oi)
                acc[oi] += xv * w1p[oi * CDIM + c];
        }
    }

#pragma unroll
    for (int oi = 0; oi < 16; ++oi) {
        int o = og * 16 + oi;
        float v = acc[oi] + b1[o];
        comp[(((size_t)b * CCH + o) * HDIM + h) * WDIM + w] = v;
        float s = v, q = v * v;
#pragma unroll
        for (int off = 32; off >= 1; off >>= 1) {
            s += __shfl_xor(s, off, 64);
            q += __shfl_xor(q, off, 64);
        }
        if (w == 0) {
            rowsum[(size_t)bh * CCH + o] = s;
            rowsq[(size_t)bh * CCH + o] = q;
        }
    }
}

// ---------------- K2: finalize BN stats from row partials (single block) ----------------
__global__ __launch_bounds__(1024) void k2_stats(const float* __restrict__ rowsum,
                                                 const float* __restrict__ rowsq,
                                                 const float* __restrict__ gamma,
                                                 const float* __restrict__ beta,
                                                 float* __restrict__ stats) {
    const int t = threadIdx.x;
    const int o = t & 63, part = t >> 6;        // 16 parts x 32 rows
    float s = 0.f, q = 0.f;
    for (int i = 0; i < 32; ++i) {
        int bh = part * 32 + i;
        s += rowsum[(size_t)bh * CCH + o];
        q += rowsq[(size_t)bh * CCH + o];
    }
    __shared__ float ls[16][64], lq[16][64];
    ls[part][o] = s; lq[part][o] = q;
    __syncthreads();
    if (part == 0) {
        float S = 0.f, Q = 0.f;
#pragma unroll
        for (int i = 0; i < 16; ++i) { S += ls[i][o]; Q += lq[i][o]; }
        const float N = (float)(BB * HDIM * WDIM);
        float mu = S / N;
        float var = Q / N - mu * mu;
        float a = rsqrtf(var + EPSV) * gamma[o];
        stats[o] = a;
        stats[CCH + o] = beta[o] - mu * a;
    }
}

// ---------------- K3: BN/ReLU on read + 3x3 conv (zero pad), XCD-swizzled ----------------
__global__ __launch_bounds__(256) void k3_conv3(const float* __restrict__ comp,
                                                const float* __restrict__ stats,
                                                const float* __restrict__ w2,
                                                const float* __restrict__ b2,
                                                float* __restrict__ enc) {
    __shared__ float cs[3][CCH][WDIM];          // 48 KB
    __shared__ float st[2 * CCH];
    const int bid = blockIdx.x;                 // 512 blocks, chunked XCD swizzle
    const int logical = (bid & 7) * 64 + (bid >> 3);
    const int b = logical >> 6, h = logical & 63;
    const int t = threadIdx.x;

    if (t < 2 * CCH) st[t] = stats[t];
    __syncthreads();

    for (int e = t; e < 3 * CCH * 16; e += 256) {
        int dy = e >> 10;
        int rem = e & 1023;
        int o = rem >> 4, q = rem & 15;
        int hh = h + dy - 1;
        float4 v = make_float4(0.f, 0.f, 0.f, 0.f);
        if (hh >= 0 && hh < HDIM) {
            float4 raw = *(const float4*)(comp + (((size_t)b * CCH + o) * HDIM + hh) * WDIM + q * 4);
            float a = st[o], c = st[CCH + o];
            v.x = fmaxf(raw.x * a + c, 0.f);
            v.y = fmaxf(raw.y * a + c, 0.f);
            v.z = fmaxf(raw.z * a + c, 0.f);
            v.w = fmaxf(raw.w * a + c, 0.f);
        }
        *(float4*)(&cs[dy][o][q * 4]) = v;
    }
    __syncthreads();

    const int w = t & 63;
    const int jg = __builtin_amdgcn_readfirstlane(t >> 6);   // 0..3, 9 j's each
    float acc[9];
#pragma unroll
    for (int ji = 0; ji < 9; ++ji) acc[ji] = b2[jg * 9 + ji];

    for (int o = 0; o < CCH; ++o) {
#pragma unroll
        for (int dy = 0; dy < 3; ++dy) {
            float vm1 = (w > 0)  ? cs[dy][o][w - 1] : 0.f;
            float v0  = cs[dy][o][w];
            float vp1 = (w < 63) ? cs[dy][o][w + 1] : 0.f;
#pragma unroll
            for (int ji = 0; ji < 9; ++ji) {
                int j = jg * 9 + ji;
                const float* wp = w2 + (((size_t)j * CCH + o) * 3 + dy) * 3;
                acc[ji] += vm1 * wp[0] + v0 * wp[1] + vp1 * wp[2];
            }
        }
    }
#pragma unroll
    for (int ji = 0; ji < 9; ++ji) {
        int j = jg * 9 + ji;
        enc[(((size_t)b * KJ + j) * HDIM + h) * WDIM + w] = acc[ji];
    }
}

// ---------------- K4: softmax column stats over H per (b,j,w) ----------------
__global__ __launch_bounds__(256) void k4_smstats(const float* __restrict__ enc,
                                                  float* __restrict__ mx,
                                                  float* __restrict__ ivs) {
    const int bj = blockIdx.x;                  // b*36 + j
    const int t = threadIdx.x;
    const int w = t & 63, q = t >> 6;
    const float* p = enc + (size_t)bj * HDIM * WDIM + (size_t)q * 16 * WDIM + w;
    float v[16];
    float lm = -1e30f;
#pragma unroll
    for (int i = 0; i < 16; ++i) { v[i] = p[i * WDIM]; lm = fmaxf(lm, v[i]); }

    __shared__ float red[4][WDIM];
    red[q][w] = lm;
    __syncthreads();
    float gm = fmaxf(fmaxf(red[0][w], red[1][w]), fmaxf(red[2][w], red[3][w]));
    __syncthreads();
    float ls = 0.f;
#pragma unroll
    for (int i = 0; i < 16; ++i) ls += __expf(v[i] - gm);
    red[q][w] = ls;
    __syncthreads();
    if (q == 0) {
        float s = red[0][w] + red[1][w] + red[2][w] + red[3][w];
        mx[(size_t)bj * WDIM + w] = gm;
        ivs[(size_t)bj * WDIM + w] = 1.f / s;
    }
}

// ---------------- K5: CARAFE gather + scatter, 2048 blocks, XCD-swizzled ----------------
__global__ __launch_bounds__(256) void k5_carafe(const float* __restrict__ x,
                                                 const float* __restrict__ enc,
                                                 const float* __restrict__ mx,
                                                 const float* __restrict__ ivs,
                                                 float* __restrict__ out) {
    __shared__ float ks[KJ][WDIM];              // 9 KB
    const int bid = blockIdx.x;                 // 2048 blocks, chunked XCD swizzle
    const int logical = (bid & 7) * 256 + (bid >> 3);
    const int b = logical >> 8;
    const int rem = logical & 255;
    const int h = rem >> 2, cg = rem & 3;       // cg: 64-channel chunk
    const int t = threadIdx.x;

    for (int e = t; e < KJ * WDIM; e += 256) {
        int j = e >> 6, w = e & 63;
        size_t bjw = ((size_t)b * KJ + j) * WDIM + w;
        float raw = enc[((size_t)b * KJ + j) * HDIM * WDIM + (size_t)h * WDIM + w];
        ks[j][w] = __expf(raw - mx[bjw]) * ivs[bjw];
    }
    __syncthreads();

    const int w = t & 63;
    const int sub = t >> 6;                     // 4 sub-chunks of 16 channels

    float kern[KJ];
#pragma unroll
    for (int j = 0; j < KJ; ++j) kern[j] = ks[j][w];

    const int hm1 = (h > 0) ? h - 1 : 0, hp1 = (h < 63) ? h + 1 : 63;
    const int wm1 = (w > 0) ? w - 1 : 0, wp1 = (w < 63) ? w + 1 : 63;

    for (int ci = 0; ci < 16; ++ci) {
        int c = cg * 64 + sub * 16 + ci;
        const float* xb = x + ((size_t)b * CDIM + c) * HDIM * WDIM;
        float r0 = xb[hm1 * WDIM + w];
        float r1 = xb[h   * WDIM + w];
        float r2 = xb[hp1 * WDIM + w];
        float tap[9];
        tap[0] = __shfl(r0, wm1, 64); tap[1] = r0; tap[2] = __shfl(r0, wp1, 64);
        tap[3] = __shfl(r1, wm1, 64); tap[4] = r1; tap[5] = __shfl(r1, wp1, 64);
        tap[6] = __shfl(r2, wm1, 64); tap[7] = r2; tap[8] = __shfl(r2, wp1, 64);

        float o0 = 0.f, o1 = 0.f, o2 = 0.f, o3 = 0.f;
#pragma unroll
        for (int k = 0; k < 9; ++k) {
            float tv = tap[k];
            o0 += tv * kern[0 * 9 + k];
            o1 += tv * kern[1 * 9 + k];
            o2 += tv * kern[2 * 9 + k];
            o3 += tv * kern[3 * 9 + k];
        }
        // out[b, s*64 + c/4, 2h + ((c>>1)&1), (c&1)*64 + w]
        int c2b = c >> 2;
        int hs = 2 * h + ((c >> 1) & 1);
        int wsx = (c & 1) * 64 + w;
        size_t base = ((size_t)b * CDIM) * (128 * 128) + (size_t)hs * 128 + wsx;
        out[base + (size_t)(0 * 64 + c2b) * (128 * 128)] = o0;
        out[base + (size_t)(1 * 64 + c2b) * (128 * 128)] = o1;
        out[base + (size_t)(2 * 64 + c2b) * (128 * 128)] = o2;
        out[base + (size_t)(3 * 64 + c2b) * (128 * 128)] = o3;
    }
}

extern "C" void kernel_launch(void* const* d_in, const int* in_sizes, int n_in,
                              void* d_out, int out_size, void* d_ws, size_t ws_size,
                              hipStream_t stream) {
    const float* x     = (const float*)d_in[0];
    const float* w1    = (const float*)d_in[1];
    const float* b1    = (const float*)d_in[2];
    const float* gamma = (const float*)d_in[3];
    const float* beta  = (const float*)d_in[4];
    const float* w2    = (const float*)d_in[5];
    const float* b2    = (const float*)d_in[6];
    float* out = (float*)d_out;

    char* ws = (char*)d_ws;
    float* comp   = (float*)(ws);                      // 8,388,608 B
    float* enc    = (float*)(ws + 8388608);            // 4,718,592 B
    float* mx     = (float*)(ws + 13107200);           // 73,728 B
    float* ivs    = (float*)(ws + 13180928);           // 73,728 B
    float* rowsum = (float*)(ws + 13254656);           // 131,072 B
    float* rowsq  = (float*)(ws + 13385728);           // 131,072 B
    float* stats  = (float*)(ws + 13516800);           // 512 B

    hipLaunchKernelGGL(k1_conv1x1, dim3(BB * HDIM),     dim3(256),  0, stream, x, w1, b1, comp, rowsum, rowsq);
    hipLaunchKernelGGL(k2_stats,   dim3(1),             dim3(1024), 0, stream, rowsum, rowsq, gamma, beta, stats);
    hipLaunchKernelGGL(k3_conv3,   dim3(BB * HDIM),     dim3(256),  0, stream, comp, stats, w2, b2, enc);
    hipLaunchKernelGGL(k4_smstats, dim3(BB * KJ),       dim3(256),  0, stream, enc, mx, ivs);
    hipLaunchKernelGGL(k5_carafe,  dim3(BB * HDIM * 4), dim3(256),  0, stream, x, enc, mx, ivs, out);
}

// Round 4
// 118.119 us; speedup vs baseline: 1.5452x; 1.0020x over previous
//
#include <hip/hip_runtime.h>
#include <math.h>

#define BB 8
#define CDIM 256
#define CCH 64
#define HDIM 64
#define WDIM 64
#define KJ 36           // S*S*K*K
#define EPSV 1e-5f

// ---------------- K1: 1x1 conv (C=256 -> CC=64), 8 waves, 8 o/wave, XCD-swizzled ----------------
__global__ __launch_bounds__(512) void k1_conv1x1(const float* __restrict__ x,
                                                  const float* __restrict__ w1,
                                                  const float* __restrict__ b1,
                                                  float* __restrict__ comp,
                                                  float* __restrict__ rowsumT,
                                                  float* __restrict__ rowsqT) {
    __shared__ float xs[128 * WDIM];            // 32 KB: half the channels of x[b,:,h,:]
    const int bid = blockIdx.x;                 // 512 blocks, chunked XCD swizzle
    const int logical = (bid & 7) * 64 + (bid >> 3);
    const int b = logical >> 6, h = logical & 63;
    const int t = threadIdx.x;
    const int w = t & 63;
    const int og = __builtin_amdgcn_readfirstlane(t >> 6);   // 0..7, 8 o's each

    float acc[8];
#pragma unroll
    for (int oi = 0; oi < 8; ++oi) acc[oi] = 0.f;

    const float* xrow = x + ((size_t)b * CDIM) * HDIM * WDIM + (size_t)h * WDIM;

    for (int ph = 0; ph < 2; ++ph) {
        if (ph) __syncthreads();
        for (int e = t; e < 128 * 16; e += 512) {
            int c = e >> 4, q = e & 15;
            *(float4*)(xs + c * WDIM + q * 4) =
                *(const float4*)(xrow + (size_t)(ph * 128 + c) * HDIM * WDIM + q * 4);
        }
        __syncthreads();

        const float* w1p = w1 + (size_t)og * 8 * CDIM + ph * 128;
#pragma unroll 4
        for (int c = 0; c < 128; ++c) {
            float xv = xs[c * WDIM + w];
#pragma unroll
            for (int oi = 0; oi < 8; ++oi)
                acc[oi] += xv * w1p[oi * CDIM + c];
        }
    }

#pragma unroll
    for (int oi = 0; oi < 8; ++oi) {
        int o = og * 8 + oi;
        float v = acc[oi] + b1[o];
        comp[(((size_t)b * CCH + o) * HDIM + h) * WDIM + w] = v;
        float s = v, q = v * v;
#pragma unroll
        for (int off = 32; off >= 1; off >>= 1) {
            s += __shfl_xor(s, off, 64);
            q += __shfl_xor(q, off, 64);
        }
        if (w == 0) {
            rowsumT[(size_t)o * 512 + logical] = s;
            rowsqT[(size_t)o * 512 + logical] = q;
        }
    }
}

// ---------------- K2: finalize BN stats, one block per channel ----------------
__global__ __launch_bounds__(256) void k2_stats(const float* __restrict__ rowsumT,
                                                const float* __restrict__ rowsqT,
                                                const float* __restrict__ gamma,
                                                const float* __restrict__ beta,
                                                float* __restrict__ stats) {
    const int o = blockIdx.x;                   // 64 blocks
    const int t = threadIdx.x;
    float s = rowsumT[(size_t)o * 512 + t] + rowsumT[(size_t)o * 512 + t + 256];
    float q = rowsqT[(size_t)o * 512 + t] + rowsqT[(size_t)o * 512 + t + 256];
#pragma unroll
    for (int off = 32; off >= 1; off >>= 1) {
        s += __shfl_xor(s, off, 64);
        q += __shfl_xor(q, off, 64);
    }
    __shared__ float ls[4], lq[4];
    const int wave = t >> 6, lane = t & 63;
    if (lane == 0) { ls[wave] = s; lq[wave] = q; }
    __syncthreads();
    if (t == 0) {
        float S = ls[0] + ls[1] + ls[2] + ls[3];
        float Q = lq[0] + lq[1] + lq[2] + lq[3];
        const float N = (float)(BB * HDIM * WDIM);
        float mu = S / N;
        float var = Q / N - mu * mu;
        float a = rsqrtf(var + EPSV) * gamma[o];
        stats[o] = a;
        stats[CCH + o] = beta[o] - mu * a;
    }
}

// ---------------- K3: BN/ReLU on read + 3x3 conv (zero pad), 8 waves, XCD-swizzled ----------------
__global__ __launch_bounds__(512) void k3_conv3(const float* __restrict__ comp,
                                                const float* __restrict__ stats,
                                                const float* __restrict__ w2,
                                                const float* __restrict__ b2,
                                                float* __restrict__ enc) {
    __shared__ float cs[3][CCH][WDIM];          // 48 KB
    __shared__ float st[2 * CCH];
    const int bid = blockIdx.x;                 // 512 blocks, chunked XCD swizzle
    const int logical = (bid & 7) * 64 + (bid >> 3);
    const int b = logical >> 6, h = logical & 63;
    const int t = threadIdx.x;

    if (t < 2 * CCH) st[t] = stats[t];
    __syncthreads();

    for (int e = t; e < 3 * CCH * 16; e += 512) {
        int dy = e >> 10;
        int rem = e & 1023;
        int o = rem >> 4, q = rem & 15;
        int hh = h + dy - 1;
        float4 v = make_float4(0.f, 0.f, 0.f, 0.f);
        if (hh >= 0 && hh < HDIM) {
            float4 raw = *(const float4*)(comp + (((size_t)b * CCH + o) * HDIM + hh) * WDIM + q * 4);
            float a = st[o], c = st[CCH + o];
            v.x = fmaxf(raw.x * a + c, 0.f);
            v.y = fmaxf(raw.y * a + c, 0.f);
            v.z = fmaxf(raw.z * a + c, 0.f);
            v.w = fmaxf(raw.w * a + c, 0.f);
        }
        *(float4*)(&cs[dy][o][q * 4]) = v;
    }
    __syncthreads();

    const int w = t & 63;
    const int jg = __builtin_amdgcn_readfirstlane(t >> 6);   // 0..7
    const int jcnt = (jg < 4) ? 5 : 4;                       // j = jg + 8*ji, 36 total
    float acc[5];
#pragma unroll
    for (int ji = 0; ji < 5; ++ji)
        acc[ji] = (ji < jcnt) ? b2[jg + 8 * ji] : 0.f;

    for (int o = 0; o < CCH; ++o) {
#pragma unroll
        for (int dy = 0; dy < 3; ++dy) {
            float vm1 = (w > 0)  ? cs[dy][o][w - 1] : 0.f;
            float v0  = cs[dy][o][w];
            float vp1 = (w < 63) ? cs[dy][o][w + 1] : 0.f;
#pragma unroll
            for (int ji = 0; ji < 5; ++ji) {
                if (ji < jcnt) {
                    int j = jg + 8 * ji;
                    const float* wp = w2 + (((size_t)j * CCH + o) * 3 + dy) * 3;
                    acc[ji] += vm1 * wp[0] + v0 * wp[1] + vp1 * wp[2];
                }
            }
        }
    }
#pragma unroll
    for (int ji = 0; ji < 5; ++ji) {
        if (ji < jcnt) {
            int j = jg + 8 * ji;
            enc[(((size_t)b * KJ + j) * HDIM + h) * WDIM + w] = acc[ji];
        }
    }
}

// ---------------- K4: softmax column stats over H per (b,j,w), XCD-swizzled ----------------
__global__ __launch_bounds__(256) void k4_smstats(const float* __restrict__ enc,
                                                  float* __restrict__ mx,
                                                  float* __restrict__ ivs) {
    const int bid = blockIdx.x;                 // 288 = 8*36, chunked XCD swizzle
    const int b = bid & 7, j = bid >> 3;
    const int bj = b * KJ + j;
    const int t = threadIdx.x;
    const int w = t & 63, q = t >> 6;
    const float* p = enc + (size_t)bj * HDIM * WDIM + (size_t)q * 16 * WDIM + w;
    float v[16];
    float lm = -1e30f;
#pragma unroll
    for (int i = 0; i < 16; ++i) { v[i] = p[i * WDIM]; lm = fmaxf(lm, v[i]); }

    __shared__ float red[4][WDIM];
    red[q][w] = lm;
    __syncthreads();
    float gm = fmaxf(fmaxf(red[0][w], red[1][w]), fmaxf(red[2][w], red[3][w]));
    __syncthreads();
    float ls = 0.f;
#pragma unroll
    for (int i = 0; i < 16; ++i) ls += __expf(v[i] - gm);
    red[q][w] = ls;
    __syncthreads();
    if (q == 0) {
        float s = red[0][w] + red[1][w] + red[2][w] + red[3][w];
        mx[(size_t)bj * WDIM + w] = gm;
        ivs[(size_t)bj * WDIM + w] = 1.f / s;
    }
}

// ---------------- K5: CARAFE gather + scatter, 2048 blocks, XCD-swizzled, nt stores ----------------
__global__ __launch_bounds__(256) void k5_carafe(const float* __restrict__ x,
                                                 const float* __restrict__ enc,
                                                 const float* __restrict__ mx,
                                                 const float* __restrict__ ivs,
                                                 float* __restrict__ out) {
    __shared__ float ks[KJ][WDIM];              // 9 KB
    const int bid = blockIdx.x;                 // 2048 blocks, chunked XCD swizzle
    const int logical = (bid & 7) * 256 + (bid >> 3);
    const int b = logical >> 8;
    const int rem = logical & 255;
    const int h = rem >> 2, cg = rem & 3;       // cg: 64-channel chunk
    const int t = threadIdx.x;

    for (int e = t; e < KJ * WDIM; e += 256) {
        int j = e >> 6, w = e & 63;
        size_t bjw = ((size_t)b * KJ + j) * WDIM + w;
        float raw = enc[((size_t)b * KJ + j) * HDIM * WDIM + (size_t)h * WDIM + w];
        ks[j][w] = __expf(raw - mx[bjw]) * ivs[bjw];
    }
    __syncthreads();

    const int w = t & 63;
    const int sub = t >> 6;                     // 4 sub-chunks of 16 channels

    float kern[KJ];
#pragma unroll
    for (int j = 0; j < KJ; ++j) kern[j] = ks[j][w];

    const int hm1 = (h > 0) ? h - 1 : 0, hp1 = (h < 63) ? h + 1 : 63;
    const int wm1 = (w > 0) ? w - 1 : 0, wp1 = (w < 63) ? w + 1 : 63;

    for (int ci = 0; ci < 16; ++ci) {
        int c = cg * 64 + sub * 16 + ci;
        const float* xb = x + ((size_t)b * CDIM + c) * HDIM * WDIM;
        float r0 = xb[hm1 * WDIM + w];
        float r1 = xb[h   * WDIM + w];
        float r2 = xb[hp1 * WDIM + w];
        float tap[9];
        tap[0] = __shfl(r0, wm1, 64); tap[1] = r0; tap[2] = __shfl(r0, wp1, 64);
        tap[3] = __shfl(r1, wm1, 64); tap[4] = r1; tap[5] = __shfl(r1, wp1, 64);
        tap[6] = __shfl(r2, wm1, 64); tap[7] = r2; tap[8] = __shfl(r2, wp1, 64);

        float o0 = 0.f, o1 = 0.f, o2 = 0.f, o3 = 0.f;
#pragma unroll
        for (int k = 0; k < 9; ++k) {
            float tv = tap[k];
            o0 += tv * kern[0 * 9 + k];
            o1 += tv * kern[1 * 9 + k];
            o2 += tv * kern[2 * 9 + k];
            o3 += tv * kern[3 * 9 + k];
        }
        // out[b, s*64 + c/4, 2h + ((c>>1)&1), (c&1)*64 + w]
        int c2b = c >> 2;
        int hs = 2 * h + ((c >> 1) & 1);
        int wsx = (c & 1) * 64 + w;
        size_t base = ((size_t)b * CDIM) * (128 * 128) + (size_t)hs * 128 + wsx;
        __builtin_nontemporal_store(o0, &out[base + (size_t)(0 * 64 + c2b) * (128 * 128)]);
        __builtin_nontemporal_store(o1, &out[base + (size_t)(1 * 64 + c2b) * (128 * 128)]);
        __builtin_nontemporal_store(o2, &out[base + (size_t)(2 * 64 + c2b) * (128 * 128)]);
        __builtin_nontemporal_store(o3, &out[base + (size_t)(3 * 64 + c2b) * (128 * 128)]);
    }
}

extern "C" void kernel_launch(void* const* d_in, const int* in_sizes, int n_in,
                              void* d_out, int out_size, void* d_ws, size_t ws_size,
                              hipStream_t stream) {
    const float* x     = (const float*)d_in[0];
    const float* w1    = (const float*)d_in[1];
    const float* b1    = (const float*)d_in[2];
    const float* gamma = (const float*)d_in[3];
    const float* beta  = (const float*)d_in[4];
    const float* w2    = (const float*)d_in[5];
    const float* b2    = (const float*)d_in[6];
    float* out = (float*)d_out;

    char* ws = (char*)d_ws;
    float* comp    = (float*)(ws);                     // 8,388,608 B
    float* enc     = (float*)(ws + 8388608);           // 4,718,592 B
    float* mx      = (float*)(ws + 13107200);          // 73,728 B
    float* ivs     = (float*)(ws + 13180928);          // 73,728 B
    float* rowsumT = (float*)(ws + 13254656);          // 131,072 B
    float* rowsqT  = (float*)(ws + 13385728);          // 131,072 B
    float* stats   = (float*)(ws + 13516800);          // 512 B

    hipLaunchKernelGGL(k1_conv1x1, dim3(BB * HDIM),     dim3(512), 0, stream, x, w1, b1, comp, rowsumT, rowsqT);
    hipLaunchKernelGGL(k2_stats,   dim3(CCH),           dim3(256), 0, stream, rowsumT, rowsqT, gamma, beta, stats);
    hipLaunchKernelGGL(k3_conv3,   dim3(BB * HDIM),     dim3(512), 0, stream, comp, stats, w2, b2, enc);
    hipLaunchKernelGGL(k4_smstats, dim3(BB * KJ),       dim3(256), 0, stream, enc, mx, ivs);
    hipLaunchKernelGGL(k5_carafe,  dim3(BB * HDIM * 4), dim3(256), 0, stream, x, enc, mx, ivs, out);
}

// Round 5
// 91.725 us; speedup vs baseline: 1.9898x; 1.2878x over previous
//
#include <hip/hip_runtime.h>
#include <math.h>

#define BB 8
#define CDIM 256
#define CCH 64
#define HDIM 64
#define WDIM 64
#define KJ 36           // S*S*K*K
#define EPSV 1e-5f

typedef __attribute__((ext_vector_type(8))) short bf16x8;
typedef __attribute__((ext_vector_type(4))) float f32x4;

__device__ inline unsigned short f2bf(float f) {
    unsigned int u = __float_as_uint(f);
    unsigned int r = (u + 0x7fffu + ((u >> 16) & 1u)) >> 16;
    return (unsigned short)r;
}

// ---------------- K0: pack w1 -> bf16 [o][c]; w2 -> bf16 [j(48)][(dy*3+dx)*64+o] ----------------
__global__ __launch_bounds__(256) void k0_pack(const float* __restrict__ w1,
                                               const float* __restrict__ w2,
                                               unsigned short* __restrict__ w1b,
                                               unsigned short* __restrict__ w2b) {
    if (blockIdx.x == 0) {
        for (int i = threadIdx.x; i < CCH * CDIM; i += 256) w1b[i] = f2bf(w1[i]);
    } else {
        for (int i = threadIdx.x; i < 48 * 576; i += 256) {
            int j = i / 576, k = i % 576;
            int tap = k >> 6, o = k & 63;
            unsigned short v = 0;
            if (j < KJ) v = f2bf(w2[(size_t)(j * CCH + o) * 9 + tap]);
            w2b[i] = v;
        }
    }
}

// ---------------- K1: 1x1 conv via bf16 MFMA; fused row stats; XCD-swizzled ----------------
__global__ __launch_bounds__(256) void k1_mfma(const float* __restrict__ x,
                                               const unsigned short* __restrict__ w1b,
                                               const float* __restrict__ b1,
                                               float* __restrict__ comp,
                                               float* __restrict__ rowsumT,
                                               float* __restrict__ rowsqT) {
    __shared__ __align__(16) unsigned short xds[WDIM * CDIM];   // [w][c] bf16, swizzled, 32 KB
    const int bid = blockIdx.x;                 // 512 blocks, chunked XCD swizzle
    const int logical = (bid & 7) * 64 + (bid >> 3);
    const int b = logical >> 6, h = logical & 63;
    const int t = threadIdx.x;
    const int lane = t & 63, wv = t >> 6;
    const int l15 = lane & 15, g = lane >> 4;

    // stage x[b,:,h,:] -> bf16 LDS [w][c], row stride 512 B, byte ^= (w&7)<<4
    const float* xr = x + ((size_t)b * CDIM) * (HDIM * WDIM) + (size_t)h * WDIM;
    const int wq = t & 15;                      // w quad
#pragma unroll
    for (int it = 0; it < 8; ++it) {
        int cp = (t >> 4) + it * 16;            // c-pair 0..127
        float4 a = *(const float4*)(xr + (size_t)(2 * cp) * (HDIM * WDIM) + wq * 4);
        float4 c = *(const float4*)(xr + (size_t)(2 * cp + 1) * (HDIM * WDIM) + wq * 4);
        float av[4] = {a.x, a.y, a.z, a.w};
        float cv[4] = {c.x, c.y, c.z, c.w};
#pragma unroll
        for (int i = 0; i < 4; ++i) {
            int w = wq * 4 + i;
            unsigned int d = (unsigned int)f2bf(av[i]) | ((unsigned int)f2bf(cv[i]) << 16);
            *(unsigned int*)((char*)xds + w * 512 + ((4 * cp) ^ ((w & 7) << 4))) = d;
        }
    }
    __syncthreads();

    // MFMA: wave wv owns o-tile [wv*16, wv*16+16); 4 px-tiles of 16; K=256 in 8 steps
    f32x4 acc[4] = {};
    const int orow = wv * 16 + l15;
#pragma unroll
    for (int ks = 0; ks < 8; ++ks) {
        int cb = ks * 64 + g * 16;              // byte offset of this lane's 8 c's
        bf16x8 afrag = *(const bf16x8*)((const char*)w1b + orow * 512 + cb);
#pragma unroll
        for (int pt = 0; pt < 4; ++pt) {
            int wrow = pt * 16 + l15;
            bf16x8 bfrag = *(bf16x8*)((char*)xds + wrow * 512 + (cb ^ ((wrow & 7) << 4)));
            acc[pt] = __builtin_amdgcn_mfma_f32_16x16x32_bf16(afrag, bfrag, acc[pt], 0, 0, 0);
        }
    }

    // epilogue: D[o = wv*16 + g*4 + r][w = pt*16 + l15]; bias, store, row stats
#pragma unroll
    for (int r = 0; r < 4; ++r) {
        int o = wv * 16 + g * 4 + r;
        float bias = b1[o];
        float s = 0.f, q = 0.f;
#pragma unroll
        for (int pt = 0; pt < 4; ++pt) {
            float v = acc[pt][r] + bias;
            int w = pt * 16 + l15;
            comp[(((size_t)b * CCH + o) * HDIM + h) * WDIM + w] = v;
            s += v; q += v * v;
        }
#pragma unroll
        for (int off = 1; off < 16; off <<= 1) {
            s += __shfl_xor(s, off, 64);
            q += __shfl_xor(q, off, 64);
        }
        if (l15 == 0) {
            rowsumT[(size_t)o * 512 + logical] = s;
            rowsqT[(size_t)o * 512 + logical] = q;
        }
    }
}

// ---------------- K2: finalize BN stats, one block per channel ----------------
__global__ __launch_bounds__(256) void k2_stats(const float* __restrict__ rowsumT,
                                                const float* __restrict__ rowsqT,
                                                const float* __restrict__ gamma,
                                                const float* __restrict__ beta,
                                                float* __restrict__ stats) {
    const int o = blockIdx.x;                   // 64 blocks
    const int t = threadIdx.x;
    float s = rowsumT[(size_t)o * 512 + t] + rowsumT[(size_t)o * 512 + t + 256];
    float q = rowsqT[(size_t)o * 512 + t] + rowsqT[(size_t)o * 512 + t + 256];
#pragma unroll
    for (int off = 32; off >= 1; off >>= 1) {
        s += __shfl_xor(s, off, 64);
        q += __shfl_xor(q, off, 64);
    }
    __shared__ float ls[4], lq[4];
    const int wave = t >> 6, lane = t & 63;
    if (lane == 0) { ls[wave] = s; lq[wave] = q; }
    __syncthreads();
    if (t == 0) {
        float S = ls[0] + ls[1] + ls[2] + ls[3];
        float Q = lq[0] + lq[1] + lq[2] + lq[3];
        const float N = (float)(BB * HDIM * WDIM);
        float mu = S / N;
        float var = Q / N - mu * mu;
        float a = rsqrtf(var + EPSV) * gamma[o];
        stats[o] = a;
        stats[CCH + o] = beta[o] - mu * a;
    }
}

// ---------------- K3: BN/ReLU + 3x3 conv via bf16 MFMA (implicit GEMM), XCD-swizzled ----------------
__global__ __launch_bounds__(256) void k3_mfma(const float* __restrict__ comp,
                                               const float* __restrict__ stats,
                                               const unsigned short* __restrict__ w2b,
                                               const float* __restrict__ b2,
                                               float* __restrict__ enc) {
    __shared__ __align__(16) unsigned short cds[3 * 66 * CCH];  // rows R=dy*66+wcol, 64 o each; 25 KB
    __shared__ float st[2 * CCH];
    const int bid = blockIdx.x;                 // 512 blocks, chunked XCD swizzle
    const int logical = (bid & 7) * 64 + (bid >> 3);
    const int b = logical >> 6, h = logical & 63;
    const int t = threadIdx.x;
    const int lane = t & 63, wv = t >> 6;
    const int l15 = lane & 15, g = lane >> 4;

    if (t < 2 * CCH) st[t] = stats[t];
    __syncthreads();

    // stage 3 rows of post-BN/ReLU comp as bf16, layout [R][o], byte ^= (R&7)<<4
    for (int idx = t; idx < 3 * 32 * WDIM; idx += 256) {
        int dy = idx >> 11, rem = idx & 2047;
        int op = rem >> 6, w = rem & 63;
        int hh = h + dy - 1;
        unsigned int d = 0;
        if (hh >= 0 && hh < HDIM) {
            int o0 = 2 * op;
            float v0 = fmaxf(comp[(((size_t)b * CCH + o0) * HDIM + hh) * WDIM + w] * st[o0] + st[CCH + o0], 0.f);
            float v1 = fmaxf(comp[(((size_t)b * CCH + o0 + 1) * HDIM + hh) * WDIM + w] * st[o0 + 1] + st[CCH + o0 + 1], 0.f);
            d = (unsigned int)f2bf(v0) | ((unsigned int)f2bf(v1) << 16);
        }
        int R = dy * 66 + (w + 1);
        *(unsigned int*)((char*)cds + R * 128 + ((4 * op) ^ ((R & 7) << 4))) = d;
    }
    // halo columns (w=-1 and w=64) = zero
    for (int idx = t; idx < 3 * 2 * 32; idx += 256) {
        int dy = idx >> 6, rem = idx & 63;
        int col = (rem >> 5) ? 65 : 0, op = rem & 31;
        int R = dy * 66 + col;
        *(unsigned int*)((char*)cds + R * 128 + ((4 * op) ^ ((R & 7) << 4))) = 0u;
    }
    __syncthreads();

    // implicit GEMM: wave wv owns px-tile [wv*16, wv*16+16); 3 j-tiles; K=576 in 18 steps
    f32x4 acc3[3] = {};
    const int px = wv * 16 + l15;
#pragma unroll
    for (int ks = 0; ks < 18; ++ks) {
        int k0 = ks * 32 + g * 8;               // this lane's 8 k's: (dy,dx, o0..o0+7)
        int dy = k0 / 192, rm = k0 % 192;
        int dx = rm >> 6, o0 = rm & 63;
        int R = dy * 66 + px + dx;
        bf16x8 bfrag = *(bf16x8*)((char*)cds + R * 128 + ((2 * o0) ^ ((R & 7) << 4)));
#pragma unroll
        for (int jt = 0; jt < 3; ++jt) {
            int j = jt * 16 + l15;
            bf16x8 afrag = *(const bf16x8*)((const char*)w2b + (size_t)(j * 576 + k0) * 2);
            acc3[jt] = __builtin_amdgcn_mfma_f32_16x16x32_bf16(afrag, bfrag, acc3[jt], 0, 0, 0);
        }
    }

    // epilogue: D[j = jt*16 + g*4 + r][px]; add b2, store (j<36)
#pragma unroll
    for (int jt = 0; jt < 3; ++jt) {
#pragma unroll
        for (int r = 0; r < 4; ++r) {
            int j = jt * 16 + g * 4 + r;
            if (j < KJ) {
                float v = acc3[jt][r] + b2[j];
                enc[(((size_t)b * KJ + j) * HDIM + h) * WDIM + px] = v;
            }
        }
    }
}

// ---------------- K4: softmax column stats over H per (b,j,w), XCD-swizzled ----------------
__global__ __launch_bounds__(256) void k4_smstats(const float* __restrict__ enc,
                                                  float* __restrict__ mx,
                                                  float* __restrict__ ivs) {
    const int bid = blockIdx.x;                 // 288 = 8*36
    const int b = bid & 7, j = bid >> 3;
    const int bj = b * KJ + j;
    const int t = threadIdx.x;
    const int w = t & 63, q = t >> 6;
    const float* p = enc + (size_t)bj * HDIM * WDIM + (size_t)q * 16 * WDIM + w;
    float v[16];
    float lm = -1e30f;
#pragma unroll
    for (int i = 0; i < 16; ++i) { v[i] = p[i * WDIM]; lm = fmaxf(lm, v[i]); }

    __shared__ float red[4][WDIM];
    red[q][w] = lm;
    __syncthreads();
    float gm = fmaxf(fmaxf(red[0][w], red[1][w]), fmaxf(red[2][w], red[3][w]));
    __syncthreads();
    float ls = 0.f;
#pragma unroll
    for (int i = 0; i < 16; ++i) ls += __expf(v[i] - gm);
    red[q][w] = ls;
    __syncthreads();
    if (q == 0) {
        float s = red[0][w] + red[1][w] + red[2][w] + red[3][w];
        mx[(size_t)bj * WDIM + w] = gm;
        ivs[(size_t)bj * WDIM + w] = 1.f / s;
    }
}

// ---------------- K5: CARAFE gather + scatter, 2048 blocks, XCD-swizzled, nt stores ----------------
__global__ __launch_bounds__(256) void k5_carafe(const float* __restrict__ x,
                                                 const float* __restrict__ enc,
                                                 const float* __restrict__ mx,
                                                 const float* __restrict__ ivs,
                                                 float* __restrict__ out) {
    __shared__ float ks[KJ][WDIM];              // 9 KB
    const int bid = blockIdx.x;
    const int logical = (bid & 7) * 256 + (bid >> 3);
    const int b = logical >> 8;
    const int rem = logical & 255;
    const int h = rem >> 2, cg = rem & 3;
    const int t = threadIdx.x;

    for (int e = t; e < KJ * WDIM; e += 256) {
        int j = e >> 6, w = e & 63;
        size_t bjw = ((size_t)b * KJ + j) * WDIM + w;
        float raw = enc[((size_t)b * KJ + j) * HDIM * WDIM + (size_t)h * WDIM + w];
        ks[j][w] = __expf(raw - mx[bjw]) * ivs[bjw];
    }
    __syncthreads();

    const int w = t & 63;
    const int sub = t >> 6;

    float kern[KJ];
#pragma unroll
    for (int j = 0; j < KJ; ++j) kern[j] = ks[j][w];

    const int hm1 = (h > 0) ? h - 1 : 0, hp1 = (h < 63) ? h + 1 : 63;
    const int wm1 = (w > 0) ? w - 1 : 0, wp1 = (w < 63) ? w + 1 : 63;

    for (int ci = 0; ci < 16; ++ci) {
        int c = cg * 64 + sub * 16 + ci;
        const float* xb = x + ((size_t)b * CDIM + c) * HDIM * WDIM;
        float r0 = xb[hm1 * WDIM + w];
        float r1 = xb[h   * WDIM + w];
        float r2 = xb[hp1 * WDIM + w];
        float tap[9];
        tap[0] = __shfl(r0, wm1, 64); tap[1] = r0; tap[2] = __shfl(r0, wp1, 64);
        tap[3] = __shfl(r1, wm1, 64); tap[4] = r1; tap[5] = __shfl(r1, wp1, 64);
        tap[6] = __shfl(r2, wm1, 64); tap[7] = r2; tap[8] = __shfl(r2, wp1, 64);

        float o0 = 0.f, o1 = 0.f, o2 = 0.f, o3 = 0.f;
#pragma unroll
        for (int k = 0; k < 9; ++k) {
            float tv = tap[k];
            o0 += tv * kern[0 * 9 + k];
            o1 += tv * kern[1 * 9 + k];
            o2 += tv * kern[2 * 9 + k];
            o3 += tv * kern[3 * 9 + k];
        }
        int c2b = c >> 2;
        int hs = 2 * h + ((c >> 1) & 1);
        int wsx = (c & 1) * 64 + w;
        size_t base = ((size_t)b * CDIM) * (128 * 128) + (size_t)hs * 128 + wsx;
        __builtin_nontemporal_store(o0, &out[base + (size_t)(0 * 64 + c2b) * (128 * 128)]);
        __builtin_nontemporal_store(o1, &out[base + (size_t)(1 * 64 + c2b) * (128 * 128)]);
        __builtin_nontemporal_store(o2, &out[base + (size_t)(2 * 64 + c2b) * (128 * 128)]);
        __builtin_nontemporal_store(o3, &out[base + (size_t)(3 * 64 + c2b) * (128 * 128)]);
    }
}

extern "C" void kernel_launch(void* const* d_in, const int* in_sizes, int n_in,
                              void* d_out, int out_size, void* d_ws, size_t ws_size,
                              hipStream_t stream) {
    const float* x     = (const float*)d_in[0];
    const float* w1    = (const float*)d_in[1];
    const float* b1    = (const float*)d_in[2];
    const float* gamma = (const float*)d_in[3];
    const float* beta  = (const float*)d_in[4];
    const float* w2    = (const float*)d_in[5];
    const float* b2    = (const float*)d_in[6];
    float* out = (float*)d_out;

    char* ws = (char*)d_ws;
    float* comp           = (float*)(ws);               // 8,388,608 B
    float* enc            = (float*)(ws + 8388608);     // 4,718,592 B -> 13,107,200
    float* mx             = (float*)(ws + 13107200);    // 73,728 -> 13,180,928
    float* ivs            = (float*)(ws + 13180928);    // 73,728 -> 13,254,656
    float* rowsumT        = (float*)(ws + 13254656);    // 131,072 -> 13,385,728
    float* rowsqT         = (float*)(ws + 13385728);    // 131,072 -> 13,516,800
    float* stats          = (float*)(ws + 13516800);    // 512 -> 13,517,312
    unsigned short* w1b   = (unsigned short*)(ws + 13517312);  // 32,768 -> 13,550,080
    unsigned short* w2b   = (unsigned short*)(ws + 13550080);  // 55,296 -> 13,605,376

    hipLaunchKernelGGL(k0_pack,    dim3(2),             dim3(256), 0, stream, w1, w2, w1b, w2b);
    hipLaunchKernelGGL(k1_mfma,    dim3(BB * HDIM),     dim3(256), 0, stream, x, w1b, b1, comp, rowsumT, rowsqT);
    hipLaunchKernelGGL(k2_stats,   dim3(CCH),           dim3(256), 0, stream, rowsumT, rowsqT, gamma, beta, stats);
    hipLaunchKernelGGL(k3_mfma,    dim3(BB * HDIM),     dim3(256), 0, stream, comp, stats, w2b, b2, enc);
    hipLaunchKernelGGL(k4_smstats, dim3(BB * KJ),       dim3(256), 0, stream, enc, mx, ivs);
    hipLaunchKernelGGL(k5_carafe,  dim3(BB * HDIM * 4), dim3(256), 0, stream, x, enc, mx, ivs, out);
}